// Round 10
// baseline (578.387 us; speedup 1.0000x reference)
//
#include <hip/hip_runtime.h>
#include <hip/hip_cooperative_groups.h>
#include <math.h>

namespace cg = cooperative_groups;

// Problem geometry fixed by setup_inputs(): B=32, H=512, W=512.
static constexpr int IMG_W  = 512;
static constexpr int IMG_PX = 512 * 512;        // 262144
static constexpr int NIMG   = 32;
static constexpr int TILE_W = 64;
static constexpr int TILE_H = 32;
static constexpr int TPX    = IMG_W / TILE_W;   // 8
static constexpr int TPY    = IMG_W / TILE_H;   // 16
static constexpr int TILES_PER_IMG = TPX * TPY; // 128
static constexpr int FUSED_BLOCKS  = NIMG * TILES_PER_IMG;  // 4096
static constexpr int TAIL_BLOCKS   = 1408;      // covers 360448 seam edges
static constexpr int PART_TOTAL    = FUSED_BLOCKS + TAIL_BLOCKS;
static constexpr int LCAP    = 128;             // per-tile flagged-root slots (worst case <= 96)
static constexpr int FLAGBIT = 1 << 30;
static constexpr int CNTMASK = FLAGBIT - 1;
static constexpr int TPIX    = TILE_W * TILE_H; // 2048

// ---------------- global union-find (Playne-style BUF) ----------------

__device__ __forceinline__ int find_root_g(const int* L, int x) {
    int p = L[x];
    while (p != x) { x = p; p = L[x]; }
    return x;
}

__device__ __forceinline__ void merge_g(int* L, int a, int b) {
    while (true) {
        a = find_root_g(L, a);
        b = find_root_g(L, b);
        if (a == b) return;
        if (a < b) { int t = a; a = b; b = t; }   // a > b
        int old = atomicMin(&L[a], b);
        if (old == a) return;
        a = old;
    }
}

// ---------------- LDS union-find ----------------

__device__ __forceinline__ int find_root_l(volatile int* sl, int x) {
    int p = sl[x];
    while (p != x) { x = p; p = sl[x]; }
    return p;
}

__device__ __forceinline__ void merge_l(int* sl, int a, int b) {
    while (true) {
        a = find_root_l(sl, a);
        b = find_root_l(sl, b);
        if (a == b) return;
        if (a < b) { int t = a; a = b; b = t; }
        int old = atomicMin(&sl[a], b);
        if (old == a) return;
        a = old;
    }
}

__device__ __forceinline__ void block_reduce_write(float s_fg, float s_bg,
                                                   float s_sq, float s_n,
                                                   double4* __restrict__ part,
                                                   int slot) {
    for (int o = 32; o > 0; o >>= 1) {
        s_fg += __shfl_down(s_fg, o, 64);
        s_bg += __shfl_down(s_bg, o, 64);
        s_sq += __shfl_down(s_sq, o, 64);
        s_n  += __shfl_down(s_n,  o, 64);
    }
    __shared__ double4 wsum[4];
    int wave = threadIdx.x >> 6;
    if ((threadIdx.x & 63) == 0)
        wsum[wave] = make_double4((double)s_fg, (double)s_bg, (double)s_sq, (double)s_n);
    __syncthreads();
    if (threadIdx.x == 0) {
        double4 b = wsum[0];
        for (int wv = 1; wv < 4; wv++) {
            b.x += wsum[wv].x; b.y += wsum[wv].y;
            b.z += wsum[wv].z; b.w += wsum[wv].w;
        }
        part[slot] = b;
    }
}

// fast bce at t=0: max(x,0) + log(1+exp(-|x|)), HW exp/log
__device__ __forceinline__ float bce0_fast(float xx) {
    return fmaxf(xx, 0.f) + __logf(1.f + __expf(-fabsf(xx)));
}

// ---------------- kernel 1: fused local CCL + BCE ----------------

// One block per 64x32 tile; wave64 <-> one 64-px row (8 rows/wave).
// Run-based local CCL (ballot bit-tricks; vertical merges once per stretch).
// Interior components fully resolved in-kernel; border-touching components
// emit ONE entry per component into this block's FIXED list segment
// (LDS counter, no global atomics). L written only for tile-border pixels
// (fg -> local-root link, bg -> -1) and flagged roots (self-link).
__global__ __launch_bounds__(256) void ccl_fused(const float* __restrict__ t,
                                                 const float* __restrict__ x,
                                                 int* __restrict__ L,
                                                 int* __restrict__ area,
                                                 int4* __restrict__ list,
                                                 int* __restrict__ blockcount,
                                                 double4* __restrict__ part) {
    __shared__ int   sl[TPIX];     // local label: run start / root; -1 = bg
    __shared__ int   cnt[TPIX];    // per-root count (+FLAGBIT if border)
    __shared__ float fsum[TPIX];   // per-flagged-root sum of bce(t=1)
    __shared__ unsigned long long rowmask[TILE_H];
    __shared__ int   lcount;

    int blk = blockIdx.x;
    int b   = blk / TILES_PER_IMG;
    int tid = blk % TILES_PER_IMG;
    int tY  = tid / TPX, tX = tid % TPX;
    int k   = threadIdx.x;
    int col = k & 63, wv = k >> 6;
    int base = b * IMG_PX + (tY * TILE_H) * IMG_W + tX * TILE_W;  // tile origin

    if (k == 0) lcount = 0;

    // phase 1: load t rows, ballot run masks, init labels to run starts
#pragma unroll
    for (int s = 0; s < 8; s++) {
        int row = wv * 8 + s;
        int jj  = row * TILE_W + col;
        float tv = t[base + row * IMG_W + col];
        bool fg = (tv != 0.f);
        unsigned long long mask = __ballot(fg);
        if (col == 0) rowmask[row] = mask;
        int lab = -1;
        if (fg) {
            unsigned long long startm = mask & ~(mask << 1);
            unsigned long long low = (col == 63) ? ~0ULL : ((1ULL << (col + 1)) - 1ULL);
            lab = row * TILE_W + (63 - __clzll(startm & low));
        }
        sl[jj]   = lab;
        cnt[jj]  = 0;
        fsum[jj] = 0.f;
    }
    __syncthreads();

    // phase 2: vertical merges, one per adjacency stretch
#pragma unroll
    for (int s = 0; s < 8; s++) {
        int row = wv * 8 + s;
        if (row == 0) continue;
        unsigned long long both = rowmask[row] & rowmask[row - 1];
        unsigned long long pairstart = both & ~(both << 1);
        if ((pairstart >> col) & 1ULL)
            merge_l(sl, row * TILE_W + col, (row - 1) * TILE_W + col);
    }
    __syncthreads();

    // phase 3: flatten + count (run starts only; add run length)
#pragma unroll
    for (int s = 0; s < 8; s++) {
        int row = wv * 8 + s;
        unsigned long long mask = rowmask[row];
        unsigned long long startm = mask & ~(mask << 1);
        if ((startm >> col) & 1ULL) {
            unsigned long long inv = ~(mask >> col);
            int len = inv ? (__ffsll((long long)inv) - 1) : (64 - col);
            int jj = row * TILE_W + col;
            int r = find_root_l(sl, jj);
            sl[jj] = r;
            atomicAdd(&cnt[r], len);
        }
    }
    __syncthreads();

    // phase 4: flag border comps; write L for ALL tile-border pixels
    {
        int r = -1, c = -1;
        if      (k < 64)  { r = 0;          c = k;          }  // top row
        else if (k < 128) { r = TILE_H - 1; c = k - 64;     }  // bottom row
        else if (k < 160) { r = k - 128;    c = 0;          }  // left col
        else if (k < 192) { r = k - 160;    c = TILE_W - 1; }  // right col
        if (r >= 0) {
            int jj = r * TILE_W + c;
            int g  = base + r * IMG_W + c;
            int s0 = sl[jj];
            if (s0 >= 0) {
                int root = sl[s0];                 // flattened: <=2 hops
                atomicOr(&cnt[root], FLAGBIT);
                L[g] = base + (root >> 6) * IMG_W + (root & 63);
            } else {
                L[g] = -1;                          // bg marker (poison-proof)
            }
        }
    }
    __syncthreads();

    // phase 5: BCE walk — accumulate interior, defer flagged into fsum
    float s_fg = 0.f, s_bg = 0.f, s_sq = 0.f, s_n = 0.f;
#pragma unroll
    for (int s = 0; s < 8; s++) {
        int row = wv * 8 + s;
        int jj  = row * TILE_W + col;
        float xx = x[base + row * IMG_W + col];
        float b0 = bce0_fast(xx);
        int s0 = sl[jj];
        if (s0 < 0) {
            s_bg += b0;
        } else {
            int root = sl[s0];
            int cc = cnt[root];
            float bce1 = b0 - xx;
            if (cc & FLAGBIT) {
                atomicAdd(&fsum[root], bce1);
            } else {
                float w = sqrtf((float)cc);
                s_fg += bce1 / (w + 1.f);
                s_sq += w;
                s_n  += 1.f;
            }
        }
    }
    __syncthreads();   // fsum complete before emit

    // phase 6: emit flagged roots into this block's FIXED list segment
    int4* mylist = list + blk * LCAP;
#pragma unroll
    for (int s = 0; s < 8; s++) {
        int jj = (wv * 8 + s) * TILE_W + col;
        if (sl[jj] == jj && (cnt[jj] & FLAGBIT)) {
            int slot = atomicAdd(&lcount, 1);
            int g = base + (jj >> 6) * IMG_W + (jj & 63);
            int c = cnt[jj] & CNTMASK;
            if (slot < LCAP)
                mylist[slot] = make_int4(g, __float_as_int(fsum[jj]), c, 0);
            area[g] = c;              // sparse area init at root
            L[g]    = g;              // root self-link
        }
    }
    block_reduce_write(s_fg, s_bg, s_sq, s_n, part, blk);   // internal barrier
    if (k == 0) blockcount[blk] = min(lcount, LCAP);
}

// ---------------- kernel 2: cooperative tail ----------------
// A: seam merges -> sync -> B: migrate areas -> sync -> C: deferred sums
// -> sync -> D: final loss (block 0).
__global__ __launch_bounds__(256, 6) void tail_coop(int* __restrict__ L,
                                                    int* __restrict__ area,
                                                    const int4* __restrict__ list,
                                                    const int* __restrict__ blockcount,
                                                    double4* __restrict__ part,
                                                    float* __restrict__ out,
                                                    int N) {
    cg::grid_group grid = cg::this_grid();
    int gtid = blockIdx.x * blockDim.x + threadIdx.x;
    int gstride = gridDim.x * blockDim.x;

    // phase A: cross-tile seam merges (reads L only; fg iff L >= 0)
    const int nV = (TPX - 1) * IMG_W;           // per-image vertical-seam edges
    const int nH = (TPY - 1) * IMG_W;           // per-image horizontal-seam edges
    const int perImg = nV + nH;
    const int nEdges = NIMG * perImg;           // 360448
    for (int e = gtid; e < nEdges; e += gstride) {
        int b = e / perImg;
        int v = e - b * perImg;
        int g, nbr;
        if (v < nV) {                           // vertical seams x = 64k
            int bi = v / IMG_W;
            int y  = v - bi * IMG_W;
            int xx = TILE_W * (bi + 1);
            g = b * IMG_PX + y * IMG_W + xx;
            nbr = g - 1;
        } else {                                // horizontal seams y = 32k
            int v2 = v - nV;
            int bi = v2 / IMG_W;
            int xx = v2 - bi * IMG_W;
            int y  = TILE_H * (bi + 1);
            g = b * IMG_PX + y * IMG_W + xx;
            nbr = g - IMG_W;
        }
        if (L[g] >= 0 && L[nbr] >= 0) merge_g(L, g, nbr);
    }
    grid.sync();

    // phase B: displaced flagged roots donate count to final root; compress
    const int nSlots = FUSED_BLOCKS * LCAP;
    for (int i = gtid; i < nSlots; i += gstride) {
        int blk  = i >> 7;                      // LCAP = 128
        int slot = i & (LCAP - 1);
        if (slot < blockcount[blk]) {
            int4 ent = list[i];
            int g = ent.x;
            int r = find_root_g(L, g);
            if (r != g) { atomicAdd(&area[r], ent.z); L[g] = r; }
        }
    }
    grid.sync();

    // phase C: per-component weighted sums
    float s_fg = 0.f, s_sq = 0.f, s_n = 0.f;
    for (int i = gtid; i < nSlots; i += gstride) {
        int blk  = i >> 7;
        int slot = i & (LCAP - 1);
        if (slot < blockcount[blk]) {
            int4 ent = list[i];
            int r = find_root_g(L, ent.x);
            float w = sqrtf((float)area[r]);
            float c = (float)ent.z;
            s_fg += __int_as_float(ent.y) / (w + 1.f);
            s_sq += c * w;
            s_n  += c;
        }
    }
    block_reduce_write(s_fg, 0.f, s_sq, s_n, part, FUSED_BLOCKS + blockIdx.x);
    grid.sync();

    // phase D: final reduction, block 0 only
    if (blockIdx.x == 0) {
        double fg = 0.0, bg = 0.0, sq = 0.0, nn = 0.0;
        for (int i = threadIdx.x; i < PART_TOTAL; i += blockDim.x) {
            double4 p = part[i];
            fg += p.x; bg += p.y; sq += p.z; nn += p.w;
        }
        for (int o = 32; o > 0; o >>= 1) {
            fg += __shfl_down(fg, o, 64);
            bg += __shfl_down(bg, o, 64);
            sq += __shfl_down(sq, o, 64);
            nn += __shfl_down(nn, o, 64);
        }
        __shared__ double4 fsum2[4];
        int wave = threadIdx.x >> 6;
        if ((threadIdx.x & 63) == 0) fsum2[wave] = make_double4(fg, bg, sq, nn);
        __syncthreads();
        if (threadIdx.x == 0) {
            double4 bb = fsum2[0];
            for (int wv = 1; wv < 4; wv++) {
                bb.x += fsum2[wv].x; bb.y += fsum2[wv].y;
                bb.z += fsum2[wv].z; bb.w += fsum2[wv].w;
            }
            double mean_nz = bb.z / fmax(bb.w, 1.0);
            double loss = (bb.x + bb.y / (mean_nz + 1.0)) / (double)N;
            out[0] = (float)loss;
        }
    }
}

// ---------------- launch ----------------

extern "C" void kernel_launch(void* const* d_in, const int* in_sizes, int n_in,
                              void* d_out, int out_size, void* d_ws, size_t ws_size,
                              hipStream_t stream) {
    const float* x = (const float*)d_in[0];   // logits
    const float* t = (const float*)d_in[1];   // binary targets
    float* out = (float*)d_out;
    int N = in_sizes[0];                      // B*H*W = 8388608

    // workspace layout:
    // [L: N int][area: N int][part: PART_TOTAL double4]
    // [blockcount: FUSED_BLOCKS int][list: FUSED_BLOCKS*LCAP int4]   (~76 MB)
    int* L          = (int*)d_ws;
    int* area       = L + N;
    double4* part   = (double4*)(area + N);
    int* blockcount = (int*)(part + PART_TOTAL);
    int4* list      = (int4*)(blockcount + FUSED_BLOCKS);

    // 1. fused local CCL + BCE (no memset needed: all consumed slots written)
    ccl_fused<<<FUSED_BLOCKS, 256, 0, stream>>>(t, x, L, area, list, blockcount, part);

    // 2. cooperative tail: seam merge + migrate + deferred + final
    void* args[] = { (void*)&L, (void*)&area, (void*)&list, (void*)&blockcount,
                     (void*)&part, (void*)&out, (void*)&N };
    hipLaunchCooperativeKernel((const void*)tail_coop, dim3(TAIL_BLOCKS), dim3(256),
                               args, 0, stream);
}

// Round 11
// 177.659 us; speedup vs baseline: 3.2556x; 3.2556x over previous
//
#include <hip/hip_runtime.h>
#include <math.h>

// Problem geometry fixed by setup_inputs(): B=32, H=512, W=512.
static constexpr int IMG_W  = 512;
static constexpr int IMG_PX = 512 * 512;        // 262144
static constexpr int NIMG   = 32;
static constexpr int TILE_W = 64;
static constexpr int TILE_H = 32;
static constexpr int TPX    = IMG_W / TILE_W;   // 8
static constexpr int TPY    = IMG_W / TILE_H;   // 16
static constexpr int TILES_PER_IMG = TPX * TPY; // 128
static constexpr int FUSED_BLOCKS  = NIMG * TILES_PER_IMG;  // 4096
static constexpr int DEF_BLOCKS    = 512;
static constexpr int MIG_BLOCKS    = 512;
static constexpr int PART_TOTAL    = FUSED_BLOCKS + DEF_BLOCKS;  // 4608
static constexpr int LCAP    = 128;             // per-tile flagged-root slots (worst case <= 96)
static constexpr int FLAGBIT = 1 << 30;
static constexpr int CNTMASK = FLAGBIT - 1;
static constexpr int TPIX    = TILE_W * TILE_H; // 2048

// ---------------- global union-find (Playne-style BUF) ----------------

__device__ __forceinline__ int find_root_g(const int* L, int x) {
    int p = L[x];
    while (p != x) { x = p; p = L[x]; }
    return x;
}

__device__ __forceinline__ void merge_g(int* L, int a, int b) {
    while (true) {
        a = find_root_g(L, a);
        b = find_root_g(L, b);
        if (a == b) return;
        if (a < b) { int t = a; a = b; b = t; }   // a > b
        int old = atomicMin(&L[a], b);
        if (old == a) return;
        a = old;
    }
}

// ---------------- LDS union-find ----------------

__device__ __forceinline__ int find_root_l(volatile int* sl, int x) {
    int p = sl[x];
    while (p != x) { x = p; p = sl[x]; }
    return p;
}

__device__ __forceinline__ void merge_l(int* sl, int a, int b) {
    while (true) {
        a = find_root_l(sl, a);
        b = find_root_l(sl, b);
        if (a == b) return;
        if (a < b) { int t = a; a = b; b = t; }
        int old = atomicMin(&sl[a], b);
        if (old == a) return;
        a = old;
    }
}

__device__ __forceinline__ void block_reduce_write(float s_fg, float s_bg,
                                                   float s_sq, float s_n,
                                                   double4* __restrict__ part,
                                                   int slot) {
    for (int o = 32; o > 0; o >>= 1) {
        s_fg += __shfl_down(s_fg, o, 64);
        s_bg += __shfl_down(s_bg, o, 64);
        s_sq += __shfl_down(s_sq, o, 64);
        s_n  += __shfl_down(s_n,  o, 64);
    }
    __shared__ double4 wsum[4];
    int wave = threadIdx.x >> 6;
    if ((threadIdx.x & 63) == 0)
        wsum[wave] = make_double4((double)s_fg, (double)s_bg, (double)s_sq, (double)s_n);
    __syncthreads();
    if (threadIdx.x == 0) {
        double4 b = wsum[0];
        for (int wv = 1; wv < 4; wv++) {
            b.x += wsum[wv].x; b.y += wsum[wv].y;
            b.z += wsum[wv].z; b.w += wsum[wv].w;
        }
        part[slot] = b;
    }
}

// fast bce at t=0: max(x,0) + log(1+exp(-|x|)), HW exp/log
__device__ __forceinline__ float bce0_fast(float xx) {
    return fmaxf(xx, 0.f) + __logf(1.f + __expf(-fabsf(xx)));
}

// ---------------- kernel 1: fused local CCL + BCE ----------------

// One block per 64x32 tile; wave64 <-> one 64-px row (8 rows/wave).
// Run-based local CCL; interior components fully resolved in-kernel;
// border-touching components emit one entry per component into this block's
// FIXED list segment (LDS counter, no global atomic, no memset needed).
// x is prefetched into registers during phase 1 to hide L2/L3 latency.
__global__ __launch_bounds__(256) void ccl_fused(const float* __restrict__ t,
                                                 const float* __restrict__ x,
                                                 int* __restrict__ L,
                                                 int* __restrict__ area,
                                                 int4* __restrict__ list,
                                                 int* __restrict__ blockcount,
                                                 double4* __restrict__ part,
                                                 int* __restrict__ done) {
    __shared__ int   sl[TPIX];     // local label: run start / root; -1 = bg
    __shared__ int   cnt[TPIX];    // per-root count (+FLAGBIT if border)
    __shared__ float fsum[TPIX];   // per-flagged-root sum of bce(t=1)
    __shared__ unsigned long long rowmask[TILE_H];
    __shared__ int   lcount;

    int blk = blockIdx.x;
    int b   = blk / TILES_PER_IMG;
    int tid = blk % TILES_PER_IMG;
    int tY  = tid / TPX, tX = tid % TPX;
    int k   = threadIdx.x;
    int col = k & 63, wv = k >> 6;
    int base = b * IMG_PX + (tY * TILE_H) * IMG_W + tX * TILE_W;  // tile origin

    if (k == 0) lcount = 0;
    if (blk == 0 && k == 0) *done = 0;    // init last-block counter (pre-deferred)

    // phase 1: load t rows + PREFETCH x rows; ballot run masks; init labels
    float xr[8];
#pragma unroll
    for (int s = 0; s < 8; s++) {
        int row = wv * 8 + s;
        int jj  = row * TILE_W + col;
        int g   = base + row * IMG_W + col;
        float tv = t[g];
        xr[s] = x[g];                      // consumed in phase 5
        bool fg = (tv != 0.f);
        unsigned long long mask = __ballot(fg);
        if (col == 0) rowmask[row] = mask;
        int lab = -1;
        if (fg) {
            unsigned long long startm = mask & ~(mask << 1);
            unsigned long long low = (col == 63) ? ~0ULL : ((1ULL << (col + 1)) - 1ULL);
            lab = row * TILE_W + (63 - __clzll(startm & low));
        }
        sl[jj]   = lab;
        cnt[jj]  = 0;
        fsum[jj] = 0.f;
    }
    __syncthreads();

    // phase 2: vertical merges, one per adjacency stretch
#pragma unroll
    for (int s = 0; s < 8; s++) {
        int row = wv * 8 + s;
        if (row == 0) continue;
        unsigned long long both = rowmask[row] & rowmask[row - 1];
        unsigned long long pairstart = both & ~(both << 1);
        if ((pairstart >> col) & 1ULL)
            merge_l(sl, row * TILE_W + col, (row - 1) * TILE_W + col);
    }
    __syncthreads();

    // phase 3: flatten + count (run starts only; add run length)
#pragma unroll
    for (int s = 0; s < 8; s++) {
        int row = wv * 8 + s;
        unsigned long long mask = rowmask[row];
        unsigned long long startm = mask & ~(mask << 1);
        if ((startm >> col) & 1ULL) {
            unsigned long long inv = ~(mask >> col);
            int len = inv ? (__ffsll((long long)inv) - 1) : (64 - col);
            int jj = row * TILE_W + col;
            int r = find_root_l(sl, jj);
            sl[jj] = r;
            atomicAdd(&cnt[r], len);
        }
    }
    __syncthreads();

    // phase 4: flag border comps; write L for ALL tile-border pixels
    {
        int r = -1, c = -1;
        if      (k < 64)  { r = 0;          c = k;          }  // top row
        else if (k < 128) { r = TILE_H - 1; c = k - 64;     }  // bottom row
        else if (k < 160) { r = k - 128;    c = 0;          }  // left col
        else if (k < 192) { r = k - 160;    c = TILE_W - 1; }  // right col
        if (r >= 0) {
            int jj = r * TILE_W + c;
            int g  = base + r * IMG_W + c;
            int s0 = sl[jj];
            if (s0 >= 0) {
                int root = sl[s0];                 // flattened: <=2 hops
                atomicOr(&cnt[root], FLAGBIT);
                L[g] = base + (root >> 6) * IMG_W + (root & 63);
            } else {
                L[g] = -1;                          // bg marker (poison-proof)
            }
        }
    }
    __syncthreads();

    // phase 5: BCE walk — accumulate interior, defer flagged into fsum
    float s_fg = 0.f, s_bg = 0.f, s_sq = 0.f, s_n = 0.f;
#pragma unroll
    for (int s = 0; s < 8; s++) {
        int row = wv * 8 + s;
        int jj  = row * TILE_W + col;
        float xx = xr[s];
        float b0 = bce0_fast(xx);
        int s0 = sl[jj];
        if (s0 < 0) {
            s_bg += b0;
        } else {
            int root = sl[s0];
            int cc = cnt[root];
            float bce1 = b0 - xx;
            if (cc & FLAGBIT) {
                atomicAdd(&fsum[root], bce1);
            } else {
                float w = sqrtf((float)cc);
                s_fg += bce1 / (w + 1.f);
                s_sq += w;
                s_n  += 1.f;
            }
        }
    }
    __syncthreads();   // fsum complete before emit

    // phase 6: emit flagged roots into this block's FIXED list segment
    int4* mylist = list + blk * LCAP;
#pragma unroll
    for (int s = 0; s < 8; s++) {
        int jj = (wv * 8 + s) * TILE_W + col;
        if (sl[jj] == jj && (cnt[jj] & FLAGBIT)) {
            int slot = atomicAdd(&lcount, 1);
            int g = base + (jj >> 6) * IMG_W + (jj & 63);
            int c = cnt[jj] & CNTMASK;
            if (slot < LCAP)
                mylist[slot] = make_int4(g, __float_as_int(fsum[jj]), c, 0);
            area[g] = c;              // sparse area init at root
            L[g]    = g;              // root self-link
        }
    }
    block_reduce_write(s_fg, s_bg, s_sq, s_n, part, blk);   // internal barrier
    if (k == 0) blockcount[blk] = min(lcount, LCAP);
}

// ---------------- kernel 2: cross-tile seam merges ----------------
// fg-ness encoded in L (>=0 fg link, -1 bg) — no t reads.
__global__ void ccl_border(int* __restrict__ L, int nEdges) {
    int e = blockIdx.x * blockDim.x + threadIdx.x;
    if (e >= nEdges) return;
    const int nV = (TPX - 1) * IMG_W;
    const int nH = (TPY - 1) * IMG_W;
    int perImg = nV + nH;
    int b = e / perImg;
    int v = e - b * perImg;
    int g, nbr;
    if (v < nV) {                              // vertical seams x = 64k
        int bi = v / IMG_W;
        int y  = v - bi * IMG_W;
        int xx = TILE_W * (bi + 1);
        g = b * IMG_PX + y * IMG_W + xx;
        nbr = g - 1;
    } else {                                   // horizontal seams y = 32k
        int v2 = v - nV;
        int bi = v2 / IMG_W;
        int xx = v2 - bi * IMG_W;
        int y  = TILE_H * (bi + 1);
        g = b * IMG_PX + y * IMG_W + xx;
        nbr = g - IMG_W;
    }
    if (L[g] >= 0 && L[nbr] >= 0) merge_g(L, g, nbr);
}

// ---------------- kernel 3: migrate displaced root counts ----------------
__global__ void fix_migrate(int* __restrict__ L, int* __restrict__ area,
                            const int4* __restrict__ list,
                            const int* __restrict__ blockcount) {
    const int nSlots = FUSED_BLOCKS * LCAP;
    int stride = gridDim.x * blockDim.x;
    for (int i = blockIdx.x * blockDim.x + threadIdx.x; i < nSlots; i += stride) {
        int blk  = i >> 7;                     // LCAP = 128
        int slot = i & (LCAP - 1);
        if (slot < blockcount[blk]) {
            int4 ent = list[i];
            int g = ent.x;
            int r = find_root_g(L, g);
            if (r != g) { atomicAdd(&area[r], ent.z); L[g] = r; }
        }
    }
}

// ---------------- kernel 4: deferred sums + final loss (last block) -------
__global__ __launch_bounds__(256) void deferred_final(const int4* __restrict__ list,
                                                      const int* __restrict__ blockcount,
                                                      const int* __restrict__ L,
                                                      const int* __restrict__ area,
                                                      double4* __restrict__ part,
                                                      int* __restrict__ done,
                                                      float* __restrict__ out,
                                                      int N) {
    const int nSlots = FUSED_BLOCKS * LCAP;
    float s_fg = 0.f, s_sq = 0.f, s_n = 0.f;
    int stride = gridDim.x * blockDim.x;
    for (int i = blockIdx.x * blockDim.x + threadIdx.x; i < nSlots; i += stride) {
        int blk  = i >> 7;
        int slot = i & (LCAP - 1);
        if (slot < blockcount[blk]) {
            int4 ent = list[i];
            int r = find_root_g(L, ent.x);
            float w = sqrtf((float)area[r]);
            float c = (float)ent.z;
            s_fg += __int_as_float(ent.y) / (w + 1.f);
            s_sq += c * w;
            s_n  += c;
        }
    }
    block_reduce_write(s_fg, 0.f, s_sq, s_n, part, FUSED_BLOCKS + blockIdx.x);

    // last block to finish performs the final reduction
    __shared__ int amlast;
    if (threadIdx.x == 0) {
        __threadfence();
        int old = atomicAdd(done, 1);
        amlast = (old == (int)gridDim.x - 1);
    }
    __syncthreads();
    if (!amlast) return;
    __threadfence();

    double fg = 0.0, bg = 0.0, sq = 0.0, nn = 0.0;
    for (int i = threadIdx.x; i < PART_TOTAL; i += blockDim.x) {
        double4 p = part[i];
        fg += p.x; bg += p.y; sq += p.z; nn += p.w;
    }
    for (int o = 32; o > 0; o >>= 1) {
        fg += __shfl_down(fg, o, 64);
        bg += __shfl_down(bg, o, 64);
        sq += __shfl_down(sq, o, 64);
        nn += __shfl_down(nn, o, 64);
    }
    __shared__ double4 f2[4];
    int wave = threadIdx.x >> 6;
    if ((threadIdx.x & 63) == 0) f2[wave] = make_double4(fg, bg, sq, nn);
    __syncthreads();
    if (threadIdx.x == 0) {
        double4 bb = f2[0];
        for (int wv = 1; wv < 4; wv++) {
            bb.x += f2[wv].x; bb.y += f2[wv].y;
            bb.z += f2[wv].z; bb.w += f2[wv].w;
        }
        double mean_nz = bb.z / fmax(bb.w, 1.0);
        double loss = (bb.x + bb.y / (mean_nz + 1.0)) / (double)N;
        out[0] = (float)loss;
    }
}

// ---------------- launch ----------------

extern "C" void kernel_launch(void* const* d_in, const int* in_sizes, int n_in,
                              void* d_out, int out_size, void* d_ws, size_t ws_size,
                              hipStream_t stream) {
    const float* x = (const float*)d_in[0];   // logits
    const float* t = (const float*)d_in[1];   // binary targets
    float* out = (float*)d_out;
    int N = in_sizes[0];                      // B*H*W = 8388608

    // workspace layout:
    // [L: N int][area: N int][part: PART_TOTAL double4]
    // [blockcount: FUSED_BLOCKS int][done: 4 int][list: FUSED_BLOCKS*LCAP int4]
    int* L          = (int*)d_ws;
    int* area       = L + N;
    double4* part   = (double4*)(area + N);
    int* blockcount = (int*)(part + PART_TOTAL);
    int* done       = blockcount + FUSED_BLOCKS;
    int4* list      = (int4*)(done + 4);

    // 1. fused local CCL + BCE (also zeroes the done counter)
    ccl_fused<<<FUSED_BLOCKS, 256, 0, stream>>>(t, x, L, area, list, blockcount,
                                                part, done);
    // 2. cross-tile seam merges
    const int nEdges = NIMG * ((TPX - 1) + (TPY - 1)) * IMG_W;   // 360448
    ccl_border<<<(nEdges + 255) / 256, 256, 0, stream>>>(L, nEdges);
    // 3. migrate displaced root counts to final roots
    fix_migrate<<<MIG_BLOCKS, 256, 0, stream>>>(L, area, list, blockcount);
    // 4. deferred component sums + final loss (last-block pattern)
    deferred_final<<<DEF_BLOCKS, 256, 0, stream>>>(list, blockcount, L, area,
                                                   part, done, out, N);
}

// Round 12
// 177.484 us; speedup vs baseline: 3.2588x; 1.0010x over previous
//
#include <hip/hip_runtime.h>
#include <math.h>

// Problem geometry fixed by setup_inputs(): B=32, H=512, W=512.
static constexpr int IMG_W  = 512;
static constexpr int IMG_PX = 512 * 512;        // 262144
static constexpr int NIMG   = 32;
static constexpr int TILE_W = 64;
static constexpr int TILE_H = 32;
static constexpr int TPX    = IMG_W / TILE_W;   // 8
static constexpr int TPY    = IMG_W / TILE_H;   // 16
static constexpr int TILES_PER_IMG = TPX * TPY; // 128
static constexpr int FUSED_BLOCKS  = NIMG * TILES_PER_IMG;  // 4096
static constexpr int SEAM_BLOCKS   = 512;
static constexpr int MIG_BLOCKS    = 512;
static constexpr int DEF_BLOCKS    = 512;
static constexpr int PART_TOTAL    = FUSED_BLOCKS + DEF_BLOCKS;  // 4608
static constexpr int LCAP    = 128;             // per-tile flagged-root slots (worst <= 96)
static constexpr int SCAP    = 128;             // per-tile seam-pair slots (worst <= 96)
static constexpr int FLAGBIT = 1 << 30;
static constexpr int CNTMASK = FLAGBIT - 1;
static constexpr int TPIX    = TILE_W * TILE_H; // 2048

// ---------------- global union-find (Playne-style BUF) ----------------

__device__ __forceinline__ int find_root_g(const int* L, int x) {
    int p = L[x];
    while (p != x) { x = p; p = L[x]; }
    return x;
}

__device__ __forceinline__ void merge_g(int* L, int a, int b) {
    while (true) {
        a = find_root_g(L, a);
        b = find_root_g(L, b);
        if (a == b) return;
        if (a < b) { int t = a; a = b; b = t; }   // a > b
        int old = atomicMin(&L[a], b);
        if (old == a) return;
        a = old;
    }
}

// ---------------- LDS union-find ----------------

__device__ __forceinline__ int find_root_l(volatile int* sl, int x) {
    int p = sl[x];
    while (p != x) { x = p; p = sl[x]; }
    return p;
}

__device__ __forceinline__ void merge_l(int* sl, int a, int b) {
    while (true) {
        a = find_root_l(sl, a);
        b = find_root_l(sl, b);
        if (a == b) return;
        if (a < b) { int t = a; a = b; b = t; }
        int old = atomicMin(&sl[a], b);
        if (old == a) return;
        a = old;
    }
}

__device__ __forceinline__ void block_reduce_write(float s_fg, float s_bg,
                                                   float s_sq, float s_n,
                                                   double4* __restrict__ part,
                                                   int slot) {
    for (int o = 32; o > 0; o >>= 1) {
        s_fg += __shfl_down(s_fg, o, 64);
        s_bg += __shfl_down(s_bg, o, 64);
        s_sq += __shfl_down(s_sq, o, 64);
        s_n  += __shfl_down(s_n,  o, 64);
    }
    __shared__ double4 wsum[4];
    int wave = threadIdx.x >> 6;
    if ((threadIdx.x & 63) == 0)
        wsum[wave] = make_double4((double)s_fg, (double)s_bg, (double)s_sq, (double)s_n);
    __syncthreads();
    if (threadIdx.x == 0) {
        double4 b = wsum[0];
        for (int wv = 1; wv < 4; wv++) {
            b.x += wsum[wv].x; b.y += wsum[wv].y;
            b.z += wsum[wv].z; b.w += wsum[wv].w;
        }
        part[slot] = b;
    }
}

// fast bce at t=0: max(x,0) + log(1+exp(-|x|)), HW exp/log
__device__ __forceinline__ float bce0_fast(float xx) {
    return fmaxf(xx, 0.f) + __logf(1.f + __expf(-fabsf(xx)));
}

// ---------------- kernel 1: fused local CCL + BCE ----------------

// One block per 64x32 tile; wave64 <-> one 64-px row (8 rows/wave).
// Run-based local CCL. Halo-aware flagging: a component is deferred ONLY if
// one of its border pixels has an fg neighbor across the seam (read from the
// t-halo) — i.e. only comps that will actually merge. Owner sides (bottom
// row, right col) emit explicit fg-fg seam pairs into a fixed per-tile
// worklist. Everything else is resolved and accumulated in-kernel.
__global__ __launch_bounds__(256) void ccl_fused(const float* __restrict__ t,
                                                 const float* __restrict__ x,
                                                 int* __restrict__ L,
                                                 int* __restrict__ area,
                                                 int4* __restrict__ list,
                                                 int* __restrict__ blockcount,
                                                 int2* __restrict__ seams,
                                                 int* __restrict__ seamcount,
                                                 double4* __restrict__ part,
                                                 int* __restrict__ done) {
    __shared__ int   sl[TPIX];     // local label: run start / root; -1 = bg
    __shared__ int   cnt[TPIX];    // per-root count (+FLAGBIT if will-merge)
    __shared__ float fsum[TPIX];   // per-flagged-root sum of bce(t=1)
    __shared__ unsigned long long rowmask[TILE_H];
    __shared__ int   lcount, scount;

    int blk = blockIdx.x;
    int b   = blk / TILES_PER_IMG;
    int tid = blk % TILES_PER_IMG;
    int tY  = tid / TPX, tX = tid % TPX;
    int k   = threadIdx.x;
    int col = k & 63, wv = k >> 6;
    int base = b * IMG_PX + (tY * TILE_H) * IMG_W + tX * TILE_W;  // tile origin

    if (k == 0) { lcount = 0; scount = 0; }
    if (blk == 0 && k == 0) *done = 0;    // init last-block counter

    // phase 1: load t rows + PREFETCH x rows; ballot run masks; init labels
    float xr[8];
#pragma unroll
    for (int s = 0; s < 8; s++) {
        int row = wv * 8 + s;
        int jj  = row * TILE_W + col;
        int g   = base + row * IMG_W + col;
        float tv = t[g];
        xr[s] = x[g];                      // consumed in phase 5
        bool fg = (tv != 0.f);
        unsigned long long mask = __ballot(fg);
        if (col == 0) rowmask[row] = mask;
        int lab = -1;
        if (fg) {
            unsigned long long startm = mask & ~(mask << 1);
            unsigned long long low = (col == 63) ? ~0ULL : ((1ULL << (col + 1)) - 1ULL);
            lab = row * TILE_W + (63 - __clzll(startm & low));
        }
        sl[jj]   = lab;
        cnt[jj]  = 0;
        fsum[jj] = 0.f;
    }
    __syncthreads();

    // phase 2: vertical merges, one per adjacency stretch
#pragma unroll
    for (int s = 0; s < 8; s++) {
        int row = wv * 8 + s;
        if (row == 0) continue;
        unsigned long long both = rowmask[row] & rowmask[row - 1];
        unsigned long long pairstart = both & ~(both << 1);
        if ((pairstart >> col) & 1ULL)
            merge_l(sl, row * TILE_W + col, (row - 1) * TILE_W + col);
    }
    __syncthreads();

    // phase 3: flatten + count (run starts only; add run length)
#pragma unroll
    for (int s = 0; s < 8; s++) {
        int row = wv * 8 + s;
        unsigned long long mask = rowmask[row];
        unsigned long long startm = mask & ~(mask << 1);
        if ((startm >> col) & 1ULL) {
            unsigned long long inv = ~(mask >> col);
            int len = inv ? (__ffsll((long long)inv) - 1) : (64 - col);
            int jj = row * TILE_W + col;
            int r = find_root_l(sl, jj);
            sl[jj] = r;
            atomicAdd(&cnt[r], len);
        }
    }
    __syncthreads();

    // phase 4: halo-aware border handling (192 threads).
    // For each fg border pixel: write its L chain link; if the across-seam
    // t value is fg, flag the component; owner sides emit the merge pair.
    {
        int r = -1, c = 0, dg = 0; bool owner = false;
        if      (k < 64)  { r = 0;          c = k;        dg = (tY > 0)       ? -IMG_W : 0; }
        else if (k < 128) { r = TILE_H - 1; c = k - 64;   dg = (tY < TPY - 1) ?  IMG_W : 0; owner = true; }
        else if (k < 160) { r = k - 128;    c = 0;        dg = (tX > 0)       ? -1     : 0; }
        else if (k < 192) { r = k - 160;    c = TILE_W-1; dg = (tX < TPX - 1) ?  1     : 0; owner = true; }
        if (r >= 0) {
            int jj = r * TILE_W + c;
            int s0 = sl[jj];
            if (s0 >= 0) {
                int root = sl[s0];                 // flattened: <=2 hops
                int g = base + r * IMG_W + c;
                L[g] = base + (root >> 6) * IMG_W + (root & 63);
                if (dg != 0 && t[g + dg] != 0.f) { // halo read: will merge
                    atomicOr(&cnt[root], FLAGBIT);
                    if (owner) {
                        int s = atomicAdd(&scount, 1);
                        if (s < SCAP) seams[blk * SCAP + s] = make_int2(g, g + dg);
                    }
                }
            }
        }
    }
    __syncthreads();

    // phase 5: BCE walk — accumulate interior, defer flagged into fsum
    float s_fg = 0.f, s_bg = 0.f, s_sq = 0.f, s_n = 0.f;
#pragma unroll
    for (int s = 0; s < 8; s++) {
        int row = wv * 8 + s;
        int jj  = row * TILE_W + col;
        float xx = xr[s];
        float b0 = bce0_fast(xx);
        int s0 = sl[jj];
        if (s0 < 0) {
            s_bg += b0;
        } else {
            int root = sl[s0];
            int cc = cnt[root];
            float bce1 = b0 - xx;
            if (cc & FLAGBIT) {
                atomicAdd(&fsum[root], bce1);
            } else {
                float w = sqrtf((float)cc);
                s_fg += bce1 / (w + 1.f);
                s_sq += w;
                s_n  += 1.f;
            }
        }
    }
    __syncthreads();   // fsum complete before emit

    // phase 6: emit flagged roots into this block's FIXED list segment
    int4* mylist = list + blk * LCAP;
#pragma unroll
    for (int s = 0; s < 8; s++) {
        int jj = (wv * 8 + s) * TILE_W + col;
        if (sl[jj] == jj && (cnt[jj] & FLAGBIT)) {
            int slot = atomicAdd(&lcount, 1);
            int g = base + (jj >> 6) * IMG_W + (jj & 63);
            int c = cnt[jj] & CNTMASK;
            if (slot < LCAP)
                mylist[slot] = make_int4(g, __float_as_int(fsum[jj]), c, 0);
            area[g] = c;              // sparse area init at root
            L[g]    = g;              // root self-link
        }
    }
    block_reduce_write(s_fg, s_bg, s_sq, s_n, part, blk);   // internal barrier
    if (k == 0) { blockcount[blk] = min(lcount, LCAP); seamcount[blk] = min(scount, SCAP); }
}

// ---------------- kernel 2: explicit seam-pair merges ----------------
__global__ __launch_bounds__(256) void seam_merge(int* __restrict__ L,
                                                  const int2* __restrict__ seams,
                                                  const int* __restrict__ seamcount) {
    const int nSlots = FUSED_BLOCKS * SCAP;
    int stride = gridDim.x * blockDim.x;
    for (int i = blockIdx.x * blockDim.x + threadIdx.x; i < nSlots; i += stride) {
        int blk  = i >> 7;                     // SCAP = 128
        int slot = i & (SCAP - 1);
        if (slot < seamcount[blk]) {
            int2 p = seams[i];
            merge_g(L, p.x, p.y);
        }
    }
}

// ---------------- kernel 3: migrate displaced root counts ----------------
__global__ __launch_bounds__(256) void fix_migrate(int* __restrict__ L,
                                                   int* __restrict__ area,
                                                   const int4* __restrict__ list,
                                                   const int* __restrict__ blockcount) {
    const int nSlots = FUSED_BLOCKS * LCAP;
    int stride = gridDim.x * blockDim.x;
    for (int i = blockIdx.x * blockDim.x + threadIdx.x; i < nSlots; i += stride) {
        int blk  = i >> 7;                     // LCAP = 128
        int slot = i & (LCAP - 1);
        if (slot < blockcount[blk]) {
            int4 ent = list[i];
            int g = ent.x;
            int r = find_root_g(L, g);
            if (r != g) { atomicAdd(&area[r], ent.z); L[g] = r; }
        }
    }
}

// ---------------- kernel 4: deferred sums + final loss (last block) -------
__global__ __launch_bounds__(256) void deferred_final(const int4* __restrict__ list,
                                                      const int* __restrict__ blockcount,
                                                      const int* __restrict__ L,
                                                      const int* __restrict__ area,
                                                      double4* __restrict__ part,
                                                      int* __restrict__ done,
                                                      float* __restrict__ out,
                                                      int N) {
    const int nSlots = FUSED_BLOCKS * LCAP;
    float s_fg = 0.f, s_sq = 0.f, s_n = 0.f;
    int stride = gridDim.x * blockDim.x;
    for (int i = blockIdx.x * blockDim.x + threadIdx.x; i < nSlots; i += stride) {
        int blk  = i >> 7;
        int slot = i & (LCAP - 1);
        if (slot < blockcount[blk]) {
            int4 ent = list[i];
            int r = find_root_g(L, ent.x);
            float w = sqrtf((float)area[r]);
            float c = (float)ent.z;
            s_fg += __int_as_float(ent.y) / (w + 1.f);
            s_sq += c * w;
            s_n  += c;
        }
    }
    block_reduce_write(s_fg, 0.f, s_sq, s_n, part, FUSED_BLOCKS + blockIdx.x);

    // last block to finish performs the final reduction
    __shared__ int amlast;
    if (threadIdx.x == 0) {
        __threadfence();
        int old = atomicAdd(done, 1);
        amlast = (old == (int)gridDim.x - 1);
    }
    __syncthreads();
    if (!amlast) return;
    __threadfence();

    double fg = 0.0, bg = 0.0, sq = 0.0, nn = 0.0;
    for (int i = threadIdx.x; i < PART_TOTAL; i += blockDim.x) {
        double4 p = part[i];
        fg += p.x; bg += p.y; sq += p.z; nn += p.w;
    }
    for (int o = 32; o > 0; o >>= 1) {
        fg += __shfl_down(fg, o, 64);
        bg += __shfl_down(bg, o, 64);
        sq += __shfl_down(sq, o, 64);
        nn += __shfl_down(nn, o, 64);
    }
    __shared__ double4 f2[4];
    int wave = threadIdx.x >> 6;
    if ((threadIdx.x & 63) == 0) f2[wave] = make_double4(fg, bg, sq, nn);
    __syncthreads();
    if (threadIdx.x == 0) {
        double4 bb = f2[0];
        for (int wv = 1; wv < 4; wv++) {
            bb.x += f2[wv].x; bb.y += f2[wv].y;
            bb.z += f2[wv].z; bb.w += f2[wv].w;
        }
        double mean_nz = bb.z / fmax(bb.w, 1.0);
        double loss = (bb.x + bb.y / (mean_nz + 1.0)) / (double)N;
        out[0] = (float)loss;
    }
}

// ---------------- launch ----------------

extern "C" void kernel_launch(void* const* d_in, const int* in_sizes, int n_in,
                              void* d_out, int out_size, void* d_ws, size_t ws_size,
                              hipStream_t stream) {
    const float* x = (const float*)d_in[0];   // logits
    const float* t = (const float*)d_in[1];   // binary targets
    float* out = (float*)d_out;
    int N = in_sizes[0];                      // B*H*W = 8388608

    // workspace layout:
    // [L: N int][area: N int][part: PART_TOTAL double4]
    // [blockcount: 4096 int][seamcount: 4096 int][done: 4 int]
    // [list: 4096*LCAP int4][seams: 4096*SCAP int2]   (~76.5 MB)
    int* L          = (int*)d_ws;
    int* area       = L + N;
    double4* part   = (double4*)(area + N);
    int* blockcount = (int*)(part + PART_TOTAL);
    int* seamcount  = blockcount + FUSED_BLOCKS;
    int* done       = seamcount + FUSED_BLOCKS;
    int4* list      = (int4*)(done + 4);
    int2* seams     = (int2*)(list + FUSED_BLOCKS * LCAP);

    // 1. fused local CCL + BCE (halo flagging + seam-pair emission)
    ccl_fused<<<FUSED_BLOCKS, 256, 0, stream>>>(t, x, L, area, list, blockcount,
                                                seams, seamcount, part, done);
    // 2. explicit seam merges (~32k fg-fg pairs)
    seam_merge<<<SEAM_BLOCKS, 256, 0, stream>>>(L, seams, seamcount);
    // 3. migrate displaced root counts to final roots
    fix_migrate<<<MIG_BLOCKS, 256, 0, stream>>>(L, area, list, blockcount);
    // 4. deferred component sums + final loss (last-block pattern)
    deferred_final<<<DEF_BLOCKS, 256, 0, stream>>>(list, blockcount, L, area,
                                                   part, done, out, N);
}